// Round 5
// baseline (499.604 us; speedup 1.0000x reference)
//
#include <hip/hip_runtime.h>

// Problem constants
#define B_TOK 32768
#define D_IN  256
#define H1D   512
#define H2D   256
#define NE    16
#define NO    64
#define TK    64             // tokens per block (2 blocks/CU)

typedef _Float16 half8 __attribute__((ext_vector_type(8)));
typedef _Float16 half4 __attribute__((ext_vector_type(4)));
typedef float   float4_t __attribute__((ext_vector_type(4)));

// ---------------------------------------------------------------------------
// Prep kernel (grid 402 x 256), coalesced-read version (R1, kept):
//  blocks 0..127   : W1 [E][D][H1] fp32 -> fragment-linear fp16 (LDS transpose)
//  blocks 128..383 : W2 [E][H1][H2] fp32 -> fragment-linear fp16 (LDS transpose)
//  blocks 384..400 : w3h[e][h2] = W3[e][h2][:].head_w ; c3[e] = b3[e][:].head_w
//  block  401      : pack gate_w [D][E] -> 8 B-fragments
// ---------------------------------------------------------------------------
__global__ void prep_kernel(const float* __restrict__ W1, const float* __restrict__ W2,
                            const float* __restrict__ W3, const float* __restrict__ b3,
                            const float* __restrict__ hw, const float* __restrict__ gw,
                            _Float16* __restrict__ w1p, _Float16* __restrict__ w2p,
                            float* __restrict__ w3h, float* __restrict__ c3,
                            _Float16* __restrict__ gwp) {
  __shared__ _Float16 tile[32 * 516];
  const int blk = blockIdx.x;
  const int tid = threadIdx.x;

  if (blk < 128) {
    const int e = blk >> 3, kt = blk & 7;
    const float* src = W1 + ((size_t)(e * D_IN + kt * 32)) * H1D;
    #pragma unroll
    for (int it = 0; it < 16; ++it) {
      int idx = it * 256 + tid;               // 4096 float4s = 32x512
      int r = idx >> 7, c4 = idx & 127;
      float4_t v = *(const float4_t*)(src + (size_t)r * H1D + c4 * 4);
      half4 h;
      h[0] = (_Float16)v[0]; h[1] = (_Float16)v[1];
      h[2] = (_Float16)v[2]; h[3] = (_Float16)v[3];
      *(half4*)(tile + r * 516 + c4 * 4) = h;
    }
    __syncthreads();
    const int lane = tid & 63, wv = tid >> 6;
    #pragma unroll
    for (int it = 0; it < 8; ++it) {
      int ntg = it * 4 + wv;
      half8 v;
      #pragma unroll
      for (int j = 0; j < 8; ++j)
        v[j] = tile[((lane >> 4) * 8 + j) * 516 + ntg * 16 + (lane & 15)];
      *(half8*)(w1p + ((size_t)(((e * 32 + ntg) * 8 + kt) * 64 + lane)) * 8) = v;
    }
  } else if (blk < 384) {
    const int b2i = blk - 128;
    const int e = b2i >> 4, ktg = b2i & 15;
    const float* src = W2 + ((size_t)(e * H1D + ktg * 32)) * H2D;
    #pragma unroll
    for (int it = 0; it < 8; ++it) {
      int idx = it * 256 + tid;               // 2048 float4s = 32x256
      int r = idx >> 6, c4 = idx & 63;
      float4_t v = *(const float4_t*)(src + (size_t)r * H2D + c4 * 4);
      half4 h;
      h[0] = (_Float16)v[0]; h[1] = (_Float16)v[1];
      h[2] = (_Float16)v[2]; h[3] = (_Float16)v[3];
      *(half4*)(tile + r * 260 + c4 * 4) = h;
    }
    __syncthreads();
    const int lane = tid & 63, wv = tid >> 6;
    #pragma unroll
    for (int it = 0; it < 4; ++it) {
      int ntg = it * 4 + wv;
      half8 v;
      #pragma unroll
      for (int j = 0; j < 8; ++j)
        v[j] = tile[((lane >> 4) * 8 + j) * 260 + ntg * 16 + (lane & 15)];
      *(half8*)(w2p + ((size_t)(((e * 16 + ntg) * 16 + ktg) * 64 + lane)) * 8) = v;
    }
  } else if (blk < 401) {
    int t = (blk - 384) * 256 + tid;
    if (t < NE * H2D) {
      int e = t >> 8, h = t & 255;
      float s = 0.f;
      #pragma unroll
      for (int o = 0; o < NO; ++o) s = fmaf(W3[((size_t)(e * H2D + h)) * NO + o], hw[o], s);
      w3h[t] = s;
    } else if (t < NE * H2D + NE) {
      int e = t - NE * H2D;
      float s = 0.f;
      #pragma unroll
      for (int o = 0; o < NO; ++o) s = fmaf(b3[e * NO + o], hw[o], s);
      c3[e] = s;
    }
  } else {
    for (int t = tid; t < 512; t += 256) {
      int lane = t & 63;
      int kt   = t >> 6;
      int e  = lane & 15;
      int kb = kt * 32 + (lane >> 4) * 8;
      half8 v;
      #pragma unroll
      for (int j = 0; j < 8; ++j)
        v[j] = (_Float16)gw[(kb + j) * NE + e];
      *(half8*)(gwp + (size_t)t * 8) = v;
    }
  }
}

// ---------------------------------------------------------------------------
// Fused main kernel. R5: 512 blocks x 512 threads, TK=64, ~72 KB LDS ->
// TWO blocks co-resident per CU (2 independent barrier domains; one block's
// MFMA covers the other's barrier/drain/pack).
//
// Allocator lesson (R3/R4): explicitly demanding 4 waves/EU (launch_bounds
// min=4 or amdgpu_waves_per_eu(4,4)) makes LLVM allocate to the NEXT tier
// (64 VGPR) and spill ~50 regs (WRITE_SIZE 129 MB). But (512,2) reliably
// lands at 124-128 VGPR = exactly the <=128 tier needed for 4 waves/EU.
// So: __launch_bounds__(512,2) + LDS 72KB and let resources determine
// occupancy: VGPR<=128 -> 4 waves/EU possible, LDS -> 2 blocks/CU.
//
// Per expert, per 256-col chunk (16 col-tiles, 4 token-tiles):
//   L1ch: wave w -> col-tiles {2w,2w+1} x all 4 token-tiles
//         (A=W1^T frags global, B=x frags LDS) -> frag-linear h1c -> barrier
//   L2ch: wave w -> h2col-tiles {2w,2w+1} x all 4 token-tiles
//         (A=h1c frags LDS, B=W2 frags global), accumulate -> barrier (WAR)
// Pack uses the R0-verified constants: cc=2w+i -> kt'=w, q'=2i+(q>>1).
// First-MFMA uses literal zero accumulator (statically unrolled) to cut
// zero-init ops and h2 liveness during the ch=0 L1 phase.
// ---------------------------------------------------------------------------
__global__ __launch_bounds__(512, 2) void moe_main(
    const float* __restrict__ x,
    const float* __restrict__ b1,
    const float* __restrict__ b2,
    const _Float16* __restrict__ w1p,
    const _Float16* __restrict__ w2p,
    const _Float16* __restrict__ gwp,
    const float* __restrict__ gb,
    const float* __restrict__ w3h,
    const float* __restrict__ c3,
    const float* __restrict__ head_b,
    float* __restrict__ out) {
  __shared__ _Float16 x_lds[32 * 512];             // 32 KB fragment-linear
  __shared__ _Float16 h1c[32 * 512];               // 32 KB fragment-linear chunk
  __shared__ float g_lds[TK * 17];                 // 4,352 B [token][e]
  __shared__ float fin[8 * TK];                    // 2 KB

  const int tid  = threadIdx.x;
  const int w    = tid >> 6;                       // 0..7
  const int lane = tid & 63;
  const int q    = lane >> 4;
  const int l16  = lane & 15;
  const int m0   = blockIdx.x * TK;

  const float4_t zero4 = (float4_t){0.f, 0.f, 0.f, 0.f};

  // ---- stage x tile into LDS as MFMA A-fragments: frag (nt,kt) at
  //      x_lds[(nt*8+kt)*512 + lane*8]. Wave w: token tile (w&3),
  //      k-frags (w>>2)*4 .. +3. --------------------------------------------
  {
    const int tt = w & 3, fb = (w >> 2) * 4;
    #pragma unroll
    for (int f = 0; f < 4; ++f) {
      const int kt = fb + f;
      const float* xr = x + (size_t)(m0 + tt * 16 + l16) * D_IN + kt * 32 + q * 8;
      float4_t v0 = *(const float4_t*)(xr);
      float4_t v1 = *(const float4_t*)(xr + 4);
      half8 h;
      h[0] = (_Float16)v0[0]; h[1] = (_Float16)v0[1];
      h[2] = (_Float16)v0[2]; h[3] = (_Float16)v0[3];
      h[4] = (_Float16)v1[0]; h[5] = (_Float16)v1[1];
      h[6] = (_Float16)v1[2]; h[7] = (_Float16)v1[3];
      *(half8*)(x_lds + (size_t)(tt * 8 + kt) * 512 + lane * 8) = h;
    }
  }
  __syncthreads();   // x_lds ready

  // ---- gates via MFMA + shuffle softmax; waves 0..3, token tile w ---------
  if (w < 4) {
    float gbv = gb[l16];
    float4_t lg = zero4;
    #pragma unroll
    for (int kt = 0; kt < 8; ++kt) {
      half8 xa = *(const half8*)(x_lds + (size_t)(w * 8 + kt) * 512 + lane * 8);
      half8 bfr = *(const half8*)(gwp + (size_t)kt * 512 + lane * 8);
      lg = __builtin_amdgcn_mfma_f32_16x16x32_f16(xa, bfr, lg, 0, 0, 0);
    }
    #pragma unroll
    for (int r = 0; r < 4; ++r) {
      float v = lg[r] + gbv;                       // logit[token][e=l16]
      float m = v;
      m = fmaxf(m, __shfl_xor(m, 1));
      m = fmaxf(m, __shfl_xor(m, 2));
      m = fmaxf(m, __shfl_xor(m, 4));
      m = fmaxf(m, __shfl_xor(m, 8));
      float p = __expf(v - m);
      float s = p;
      s += __shfl_xor(s, 1);
      s += __shfl_xor(s, 2);
      s += __shfl_xor(s, 4);
      s += __shfl_xor(s, 8);
      g_lds[(w * 16 + q * 4 + r) * 17 + l16] = p / s;
    }
  }
  // g_lds becomes visible via in-loop barriers before first epilogue read.

  float yacc[4][4];    // gated accumulator: [nt][r] for token nt*16+q*4+r
  #pragma unroll
  for (int nt = 0; nt < 4; ++nt)
    #pragma unroll
    for (int r = 0; r < 4; ++r) yacc[nt][r] = 0.f;

  for (int e = 0; e < NE; ++e) {
    float4_t h2[4][2];   // [token tile nt][h2col tile j]; first write at
                         // ch==0,kt==0 via zero-acc MFMA (statically unrolled)

    #pragma unroll
    for (int ch = 0; ch < 2; ++ch) {
      // ===== L1 chunk: wave w -> chunk col-tiles {2w,2w+1} x 4 tok-tiles ===
      float4_t a1[2][4];   // [i = col tile][nt = token tile]

      const _Float16* w1e =
          w1p + ((size_t)((e * 32 + ch * 16 + w * 2) * 8)) * 512 + lane * 8;
      #pragma unroll
      for (int kt = 0; kt < 8; ++kt) {
        half8 wc[2];
        #pragma unroll
        for (int i = 0; i < 2; ++i)
          wc[i] = *(const half8*)(w1e + (size_t)(i * 8 + kt) * 512);
        half8 xb[4];
        #pragma unroll
        for (int nt = 0; nt < 4; ++nt)
          xb[nt] = *(const half8*)(x_lds + (size_t)(nt * 8 + kt) * 512 + lane * 8);
        #pragma unroll
        for (int i = 0; i < 2; ++i)
          #pragma unroll
          for (int nt = 0; nt < 4; ++nt)
            a1[i][nt] = __builtin_amdgcn_mfma_f32_16x16x32_f16(
                wc[i], xb[nt], (kt == 0) ? zero4 : a1[i][nt], 0, 0, 0);
      }

      // bias + relu + store into FRAGMENT-LINEAR chunk layout.
      // a1[i][nt][r] = h1[tok = nt*16+l16][chunk col = (2w+i)*16 + q*4 + r].
      // cc=2w+i -> chunk k-tile kt'=w; lane' q' = 2i+(q>>1);
      // half-offset (q&1)*4 + r. (R0-verified constants.)
      #pragma unroll
      for (int i = 0; i < 2; ++i) {
        int colbase = ch * 256 + (w * 2 + i) * 16 + q * 4;   // global h1 col
        float4_t bb = *(const float4_t*)(b1 + e * H1D + colbase);
        int qp = (i << 1) + (q >> 1);
        int fo = (qp * 16 + l16) * 8 + ((q & 1) << 2);
        #pragma unroll
        for (int nt = 0; nt < 4; ++nt) {
          half4 hv;
          #pragma unroll
          for (int r = 0; r < 4; ++r)
            hv[r] = (_Float16)fmaxf(a1[i][nt][r] + bb[r], 0.f);
          *(half4*)(h1c + (size_t)(nt * 8 + w) * 512 + fo) = hv;
        }
      }

      __syncthreads();   // h1 chunk ready

      // ===== L2 partial: wave w -> h2col-tiles {2w,2w+1} x 4 tok-tiles =====
      const _Float16* w2e =
          w2p + ((size_t)((e * 16 + w * 2) * 16 + ch * 8)) * 512 + lane * 8;
      #pragma unroll
      for (int kt = 0; kt < 8; ++kt) {
        half8 w2c[2];
        #pragma unroll
        for (int j = 0; j < 2; ++j)
          w2c[j] = *(const half8*)(w2e + (size_t)(j * 16 + kt) * 512);
        half8 hac[4];
        #pragma unroll
        for (int nt = 0; nt < 4; ++nt)
          hac[nt] = *(const half8*)(h1c + (size_t)(nt * 8 + kt) * 512 + lane * 8);
        #pragma unroll
        for (int nt = 0; nt < 4; ++nt)
          #pragma unroll
          for (int j = 0; j < 2; ++j)
            h2[nt][j] = __builtin_amdgcn_mfma_f32_16x16x32_f16(
                hac[nt], w2c[j],
                (ch == 0 && kt == 0) ? zero4 : h2[nt][j], 0, 0, 0);
      }

      __syncthreads();   // WAR: h1c reads done before next chunk/expert L1
    }

    // ---- register epilogue: relu(h2+b2).w3h, gate folded, accumulate ------
    // h2[nt][j][r] = h2[tok=nt*16+q*4+r][h2col=(2w+j)*16+l16]
    float b2v[2], w3v[2];
    #pragma unroll
    for (int j = 0; j < 2; ++j) {
      int n = (w * 2 + j) * 16 + l16;
      b2v[j] = b2[e * H2D + n];
      w3v[j] = w3h[e * H2D + n];
    }
    #pragma unroll
    for (int nt = 0; nt < 4; ++nt) {
      #pragma unroll
      for (int r = 0; r < 4; ++r) {
        float s = 0.f;
        #pragma unroll
        for (int j = 0; j < 2; ++j)
          s += fmaxf(h2[nt][j][r] + b2v[j], 0.f) * w3v[j];
        yacc[nt][r] += g_lds[(nt * 16 + q * 4 + r) * 17 + e] * s;
      }
    }
  }

  // ---- final reduction: sum yacc over the 16 l16-lanes (h2col within
  //      tile), then over the 8 waves via fin[8][TK] -----------------------
  #pragma unroll
  for (int nt = 0; nt < 4; ++nt) {
    #pragma unroll
    for (int r = 0; r < 4; ++r) {
      float v = yacc[nt][r];
      v += __shfl_xor(v, 1);
      v += __shfl_xor(v, 2);
      v += __shfl_xor(v, 4);
      v += __shfl_xor(v, 8);
      yacc[nt][r] = v;
    }
  }
  if (l16 == 0) {
    #pragma unroll
    for (int nt = 0; nt < 4; ++nt)
      #pragma unroll
      for (int r = 0; r < 4; ++r)
        fin[w * TK + nt * 16 + q * 4 + r] = yacc[nt][r];
  }
  __syncthreads();
  if (tid < TK) {
    float sum = 0.f;
    #pragma unroll
    for (int k = 0; k < 8; ++k) sum += fin[k * TK + tid];
    float gc = 0.f;
    #pragma unroll
    for (int e = 0; e < NE; ++e) gc += g_lds[tid * 17 + e] * c3[e];
    out[m0 + tid] = sum + gc + head_b[0];
  }
}

// ---------------------------------------------------------------------------
extern "C" void kernel_launch(void* const* d_in, const int* in_sizes, int n_in,
                              void* d_out, int out_size, void* d_ws, size_t ws_size,
                              hipStream_t stream) {
  const float* x      = (const float*)d_in[0];
  const float* gate_w = (const float*)d_in[1];
  const float* gate_b = (const float*)d_in[2];
  const float* W1     = (const float*)d_in[3];
  const float* b1     = (const float*)d_in[4];
  const float* W2     = (const float*)d_in[5];
  const float* b2     = (const float*)d_in[6];
  const float* W3     = (const float*)d_in[7];
  const float* b3     = (const float*)d_in[8];
  const float* head_w = (const float*)d_in[9];
  const float* head_b = (const float*)d_in[10];
  float* out = (float*)d_out;

  // workspace layout (16B-aligned)
  char* ws = (char*)d_ws;
  _Float16* w1p = (_Float16*)(ws);                 // 4,194,304 B
  _Float16* w2p = (_Float16*)(ws + 4194304);       // 4,194,304 B
  _Float16* gwp = (_Float16*)(ws + 8388608);       // 8,192 B
  float*    w3h = (float*)(ws + 8396800);          // 16,384 B
  float*    c3  = (float*)(ws + 8413184);          // 64 B

  hipLaunchKernelGGL(prep_kernel, dim3(402), dim3(256), 0, stream,
                     W1, W2, W3, b3, head_w, gate_w, w1p, w2p, w3h, c3, gwp);
  hipLaunchKernelGGL(moe_main, dim3(B_TOK / TK), dim3(512), 0, stream,
                     x, b1, b2, w1p, w2p, gwp, gate_b, w3h, c3, head_b, out);
}

// Round 6
// 346.675 us; speedup vs baseline: 1.4411x; 1.4411x over previous
//
#include <hip/hip_runtime.h>

// Problem constants
#define B_TOK 32768
#define D_IN  256
#define H1D   512
#define H2D   256
#define NE    16
#define NO    64
#define TK    128            // tokens per block (R1-proven best structure)

typedef _Float16 half8 __attribute__((ext_vector_type(8)));
typedef _Float16 half4 __attribute__((ext_vector_type(4)));
typedef float   float4_t __attribute__((ext_vector_type(4)));

// LDS-only barrier: skip the vmcnt(0) drain __syncthreads() would emit.
// Both in-loop barriers protect LDS state only (h1c ready / h1c WAR), so
// lgkmcnt(0) suffices; global weight loads stay in flight across the
// barrier (this is what made R1's W2 prefetch a no-op: __syncthreads'
// vmcnt(0) forced the prefetch to complete pre-barrier).
// sched_barrier(0) on both sides pins DS ops to their side (rule #18).
#define BARRIER_LGKM() do {                                   \
    __builtin_amdgcn_sched_barrier(0);                        \
    asm volatile("s_waitcnt lgkmcnt(0)" ::: "memory");        \
    __builtin_amdgcn_s_barrier();                             \
    __builtin_amdgcn_sched_barrier(0);                        \
  } while (0)

// ---------------------------------------------------------------------------
// Prep kernel (grid 402 x 256), coalesced-read version (R1, kept):
//  blocks 0..127   : W1 [E][D][H1] fp32 -> fragment-linear fp16 (LDS transpose)
//  blocks 128..383 : W2 [E][H1][H2] fp32 -> fragment-linear fp16 (LDS transpose)
//  blocks 384..400 : w3h[e][h2] = W3[e][h2][:].head_w ; c3[e] = b3[e][:].head_w
//  block  401      : pack gate_w [D][E] -> 8 B-fragments
// ---------------------------------------------------------------------------
__global__ void prep_kernel(const float* __restrict__ W1, const float* __restrict__ W2,
                            const float* __restrict__ W3, const float* __restrict__ b3,
                            const float* __restrict__ hw, const float* __restrict__ gw,
                            _Float16* __restrict__ w1p, _Float16* __restrict__ w2p,
                            float* __restrict__ w3h, float* __restrict__ c3,
                            _Float16* __restrict__ gwp) {
  __shared__ _Float16 tile[32 * 516];
  const int blk = blockIdx.x;
  const int tid = threadIdx.x;

  if (blk < 128) {
    const int e = blk >> 3, kt = blk & 7;
    const float* src = W1 + ((size_t)(e * D_IN + kt * 32)) * H1D;
    #pragma unroll
    for (int it = 0; it < 16; ++it) {
      int idx = it * 256 + tid;               // 4096 float4s = 32x512
      int r = idx >> 7, c4 = idx & 127;
      float4_t v = *(const float4_t*)(src + (size_t)r * H1D + c4 * 4);
      half4 h;
      h[0] = (_Float16)v[0]; h[1] = (_Float16)v[1];
      h[2] = (_Float16)v[2]; h[3] = (_Float16)v[3];
      *(half4*)(tile + r * 516 + c4 * 4) = h;
    }
    __syncthreads();
    const int lane = tid & 63, wv = tid >> 6;
    #pragma unroll
    for (int it = 0; it < 8; ++it) {
      int ntg = it * 4 + wv;
      half8 v;
      #pragma unroll
      for (int j = 0; j < 8; ++j)
        v[j] = tile[((lane >> 4) * 8 + j) * 516 + ntg * 16 + (lane & 15)];
      *(half8*)(w1p + ((size_t)(((e * 32 + ntg) * 8 + kt) * 64 + lane)) * 8) = v;
    }
  } else if (blk < 384) {
    const int b2i = blk - 128;
    const int e = b2i >> 4, ktg = b2i & 15;
    const float* src = W2 + ((size_t)(e * H1D + ktg * 32)) * H2D;
    #pragma unroll
    for (int it = 0; it < 8; ++it) {
      int idx = it * 256 + tid;               // 2048 float4s = 32x256
      int r = idx >> 6, c4 = idx & 63;
      float4_t v = *(const float4_t*)(src + (size_t)r * H2D + c4 * 4);
      half4 h;
      h[0] = (_Float16)v[0]; h[1] = (_Float16)v[1];
      h[2] = (_Float16)v[2]; h[3] = (_Float16)v[3];
      *(half4*)(tile + r * 260 + c4 * 4) = h;
    }
    __syncthreads();
    const int lane = tid & 63, wv = tid >> 6;
    #pragma unroll
    for (int it = 0; it < 4; ++it) {
      int ntg = it * 4 + wv;
      half8 v;
      #pragma unroll
      for (int j = 0; j < 8; ++j)
        v[j] = tile[((lane >> 4) * 8 + j) * 260 + ntg * 16 + (lane & 15)];
      *(half8*)(w2p + ((size_t)(((e * 16 + ntg) * 16 + ktg) * 64 + lane)) * 8) = v;
    }
  } else if (blk < 401) {
    int t = (blk - 384) * 256 + tid;
    if (t < NE * H2D) {
      int e = t >> 8, h = t & 255;
      float s = 0.f;
      #pragma unroll
      for (int o = 0; o < NO; ++o) s = fmaf(W3[((size_t)(e * H2D + h)) * NO + o], hw[o], s);
      w3h[t] = s;
    } else if (t < NE * H2D + NE) {
      int e = t - NE * H2D;
      float s = 0.f;
      #pragma unroll
      for (int o = 0; o < NO; ++o) s = fmaf(b3[e * NO + o], hw[o], s);
      c3[e] = s;
    }
  } else {
    for (int t = tid; t < 512; t += 256) {
      int lane = t & 63;
      int kt   = t >> 6;
      int e  = lane & 15;
      int kb = kt * 32 + (lane >> 4) * 8;
      half8 v;
      #pragma unroll
      for (int j = 0; j < 8; ++j)
        v[j] = (_Float16)gw[(kb + j) * NE + e];
      *(half8*)(gwp + (size_t)t * 8) = v;
    }
  }
}

// ---------------------------------------------------------------------------
// Fused main kernel. R6 = R1 structure (256 blocks x 512 threads, TK=128,
// 1 block/CU — proven best at 278 us) + counted-waitcnt barrier surgery:
//  (a) in-loop barriers are lgkmcnt-only (BARRIER_LGKM): the vmcnt(0) drain
//      __syncthreads emitted each phase is gone; weight loads cross barriers.
//  (b) W2 fragment prefetch (kt 0..3) issued before barrier-1 now actually
//      stays in flight (R1's attempt was nullified by the vmcnt drain).
//  (c) register epilogue moved BEFORE the WAR barrier (reads h2 regs +
//      g_lds only), so the post-barrier critical path starts with W1 loads.
// Per-phase overhead model (R1/R5 data): 5.4k cyc/SIMD fixed overhead per
// phase; this round attacks the drain + post-barrier-stall component.
//
// Per expert, per 256-col chunk:
//   L1ch: wave w -> col-tiles {2w,2w+1} x 8 token-tiles -> h1c -> BARRIER
//   L2ch: wave w -> h2col-tiles {2w,2w+1} x 8 token-tiles, accumulate
//         (+ epilogue at ch==1) -> BARRIER (WAR)
// Pack uses the R0-verified constants: cc=2w+i -> kt'=w, q'=2i+(q>>1).
// ---------------------------------------------------------------------------
__global__ __launch_bounds__(512, 2) void moe_main(
    const float* __restrict__ x,
    const float* __restrict__ b1,
    const float* __restrict__ b2,
    const _Float16* __restrict__ w1p,
    const _Float16* __restrict__ w2p,
    const _Float16* __restrict__ gwp,
    const float* __restrict__ gb,
    const float* __restrict__ w3h,
    const float* __restrict__ c3,
    const float* __restrict__ head_b,
    float* __restrict__ out) {
  __shared__ _Float16 x_lds[64 * 512];             // 64 KB fragment-linear
  __shared__ _Float16 h1c[64 * 512];               // 64 KB fragment-linear chunk
  __shared__ float g_lds[TK * 17];                 // 8,704 B [token][e]
  __shared__ float fin[8 * TK];                    // 4 KB

  const int tid  = threadIdx.x;
  const int w    = tid >> 6;                       // 0..7
  const int lane = tid & 63;
  const int q    = lane >> 4;
  const int l16  = lane & 15;
  const int m0   = blockIdx.x * TK;

  const float4_t zero4 = (float4_t){0.f, 0.f, 0.f, 0.f};

  // ---- stage x tile into LDS as MFMA A-fragments: frag (nt,kt) at
  //      x_lds[(nt*8+kt)*512 + lane*8]; wave w stages token tile w ----------
  #pragma unroll
  for (int f = 0; f < 8; ++f) {
    const float* xr = x + (size_t)(m0 + w * 16 + l16) * D_IN + f * 32 + q * 8;
    float4_t v0 = *(const float4_t*)(xr);
    float4_t v1 = *(const float4_t*)(xr + 4);
    half8 h;
    h[0] = (_Float16)v0[0]; h[1] = (_Float16)v0[1];
    h[2] = (_Float16)v0[2]; h[3] = (_Float16)v0[3];
    h[4] = (_Float16)v1[0]; h[5] = (_Float16)v1[1];
    h[6] = (_Float16)v1[2]; h[7] = (_Float16)v1[3];
    *(half8*)(x_lds + (size_t)(w * 8 + f) * 512 + lane * 8) = h;
  }
  __syncthreads();   // x_lds ready (once; cheap)

  // ---- gates via MFMA + shuffle softmax; wave w handles token tile w ------
  {
    float gbv = gb[l16];
    float4_t lg = zero4;
    #pragma unroll
    for (int kt = 0; kt < 8; ++kt) {
      half8 xa = *(const half8*)(x_lds + (size_t)(w * 8 + kt) * 512 + lane * 8);
      half8 bfr = *(const half8*)(gwp + (size_t)kt * 512 + lane * 8);
      lg = __builtin_amdgcn_mfma_f32_16x16x32_f16(xa, bfr, lg, 0, 0, 0);
    }
    #pragma unroll
    for (int r = 0; r < 4; ++r) {
      float v = lg[r] + gbv;                       // logit[token][e=l16]
      float m = v;
      m = fmaxf(m, __shfl_xor(m, 1));
      m = fmaxf(m, __shfl_xor(m, 2));
      m = fmaxf(m, __shfl_xor(m, 4));
      m = fmaxf(m, __shfl_xor(m, 8));
      float p = __expf(v - m);
      float s = p;
      s += __shfl_xor(s, 1);
      s += __shfl_xor(s, 2);
      s += __shfl_xor(s, 4);
      s += __shfl_xor(s, 8);
      g_lds[(w * 16 + q * 4 + r) * 17 + l16] = p / s;
    }
  }
  // g_lds becomes visible via in-loop barriers before first epilogue read.

  float yacc[8][4];    // gated accumulator: [mt][r] for token mt*16+q*4+r
  #pragma unroll
  for (int mt = 0; mt < 8; ++mt)
    #pragma unroll
    for (int r = 0; r < 4; ++r) yacc[mt][r] = 0.f;

  for (int e = 0; e < NE; ++e) {
    float4_t h2[8][2];   // [token tile][h2col tile j]; first write at
                         // ch==0,kt==0 via zero-acc MFMA (statically unrolled)

    #pragma unroll
    for (int ch = 0; ch < 2; ++ch) {
      // ===== L1 chunk: wave w -> chunk col-tiles {2w, 2w+1} ================
      float4_t a1[2][8];   // [i = col tile][nt = token tile]

      const _Float16* w1e =
          w1p + ((size_t)((e * 32 + ch * 16 + w * 2) * 8)) * 512 + lane * 8;
      #pragma unroll
      for (int kt = 0; kt < 8; ++kt) {
        half8 wc[2];
        #pragma unroll
        for (int i = 0; i < 2; ++i)
          wc[i] = *(const half8*)(w1e + (size_t)(i * 8 + kt) * 512);
        half8 xb[8];
        #pragma unroll
        for (int nt = 0; nt < 8; ++nt)
          xb[nt] = *(const half8*)(x_lds + (size_t)(nt * 8 + kt) * 512 + lane * 8);
        #pragma unroll
        for (int i = 0; i < 2; ++i)
          #pragma unroll
          for (int nt = 0; nt < 8; ++nt)
            a1[i][nt] = __builtin_amdgcn_mfma_f32_16x16x32_f16(
                wc[i], xb[nt], (kt == 0) ? zero4 : a1[i][nt], 0, 0, 0);
      }

      // bias + relu + store into FRAGMENT-LINEAR chunk layout.
      // a1[i][nt][r] = h1[tok = nt*16+l16][chunk col = (2w+i)*16 + q*4 + r].
      // cc=2w+i -> chunk k-tile kt'=w; lane' q' = 2i+(q>>1);
      // half-offset (q&1)*4 + r. (R0-verified constants.)
      #pragma unroll
      for (int i = 0; i < 2; ++i) {
        int colbase = ch * 256 + (w * 2 + i) * 16 + q * 4;   // global h1 col
        float4_t bb = *(const float4_t*)(b1 + e * H1D + colbase);
        int qp = (i << 1) + (q >> 1);
        int fo = (qp * 16 + l16) * 8 + ((q & 1) << 2);
        #pragma unroll
        for (int nt = 0; nt < 8; ++nt) {
          half4 hv;
          #pragma unroll
          for (int r = 0; r < 4; ++r)
            hv[r] = (_Float16)fmaxf(a1[i][nt][r] + bb[r], 0.f);
          *(half4*)(h1c + (size_t)(nt * 8 + w) * 512 + fo) = hv;
        }
      }

      // ---- W2 fragment prefetch (kt 0..3, both j). With the lgkm-only
      //      barrier these loads remain in flight across it and land just
      //      as the L2 MFMAs need them. a1 is dead here -> no reg peak. ----
      const _Float16* w2e =
          w2p + ((size_t)((e * 16 + w * 2) * 16 + ch * 8)) * 512 + lane * 8;
      half8 w2pre[2][4];
      #pragma unroll
      for (int j = 0; j < 2; ++j)
        #pragma unroll
        for (int kt = 0; kt < 4; ++kt)
          w2pre[j][kt] = *(const half8*)(w2e + (size_t)(j * 16 + kt) * 512);

      BARRIER_LGKM();   // h1 chunk ready (LDS-only; no vmcnt drain)

      // ===== L2 partial: wave w -> h2col-tiles {2w, 2w+1} ==================
      #pragma unroll
      for (int kt = 0; kt < 4; ++kt) {
        half8 hac[8];
        #pragma unroll
        for (int mt = 0; mt < 8; ++mt)
          hac[mt] = *(const half8*)(h1c + (size_t)(mt * 8 + kt) * 512 + lane * 8);
        #pragma unroll
        for (int mt = 0; mt < 8; ++mt)
          #pragma unroll
          for (int j = 0; j < 2; ++j)
            h2[mt][j] = __builtin_amdgcn_mfma_f32_16x16x32_f16(
                hac[mt], w2pre[j][kt],
                (ch == 0 && kt == 0) ? zero4 : h2[mt][j], 0, 0, 0);
      }
      #pragma unroll
      for (int kt = 4; kt < 8; ++kt) {
        half8 w2c[2];
        #pragma unroll
        for (int j = 0; j < 2; ++j)
          w2c[j] = *(const half8*)(w2e + (size_t)(j * 16 + kt) * 512);
        half8 hac[8];
        #pragma unroll
        for (int mt = 0; mt < 8; ++mt)
          hac[mt] = *(const half8*)(h1c + (size_t)(mt * 8 + kt) * 512 + lane * 8);
        #pragma unroll
        for (int mt = 0; mt < 8; ++mt)
          #pragma unroll
          for (int j = 0; j < 2; ++j)
            h2[mt][j] = __builtin_amdgcn_mfma_f32_16x16x32_f16(
                hac[mt], w2c[j], h2[mt][j], 0, 0, 0);
      }

      // ---- register epilogue at ch==1, BEFORE the WAR barrier (reads h2
      //      regs + g_lds only; h1c untouched) so the post-barrier path
      //      starts immediately with next expert's W1 loads. ---------------
      if (ch == 1) {
        float b2v[2], w3v[2];
        #pragma unroll
        for (int j = 0; j < 2; ++j) {
          int n = (w * 2 + j) * 16 + l16;
          b2v[j] = b2[e * H2D + n];
          w3v[j] = w3h[e * H2D + n];
        }
        #pragma unroll
        for (int mt = 0; mt < 8; ++mt) {
          #pragma unroll
          for (int r = 0; r < 4; ++r) {
            float s = 0.f;
            #pragma unroll
            for (int j = 0; j < 2; ++j)
              s += fmaxf(h2[mt][j][r] + b2v[j], 0.f) * w3v[j];
            yacc[mt][r] += g_lds[(mt * 16 + q * 4 + r) * 17 + e] * s;
          }
        }
      }

      BARRIER_LGKM();   // WAR: h1c reads done before next chunk/expert L1
    }
  }

  // ---- single final reduction: sum yacc over the 16 l16-lanes (cols) ------
  #pragma unroll
  for (int mt = 0; mt < 8; ++mt) {
    #pragma unroll
    for (int r = 0; r < 4; ++r) {
      float v = yacc[mt][r];
      v += __shfl_xor(v, 1);
      v += __shfl_xor(v, 2);
      v += __shfl_xor(v, 4);
      v += __shfl_xor(v, 8);
      yacc[mt][r] = v;
    }
  }
  if (l16 == 0) {
    #pragma unroll
    for (int mt = 0; mt < 8; ++mt)
      #pragma unroll
      for (int r = 0; r < 4; ++r)
        fin[w * TK + mt * 16 + q * 4 + r] = yacc[mt][r];
  }
  __syncthreads();
  if (tid < TK) {
    float sum = 0.f;
    #pragma unroll
    for (int k = 0; k < 8; ++k) sum += fin[k * TK + tid];
    float gc = 0.f;
    #pragma unroll
    for (int e = 0; e < NE; ++e) gc += g_lds[tid * 17 + e] * c3[e];
    out[m0 + tid] = sum + gc + head_b[0];
  }
}

// ---------------------------------------------------------------------------
extern "C" void kernel_launch(void* const* d_in, const int* in_sizes, int n_in,
                              void* d_out, int out_size, void* d_ws, size_t ws_size,
                              hipStream_t stream) {
  const float* x      = (const float*)d_in[0];
  const float* gate_w = (const float*)d_in[1];
  const float* gate_b = (const float*)d_in[2];
  const float* W1     = (const float*)d_in[3];
  const float* b1     = (const float*)d_in[4];
  const float* W2     = (const float*)d_in[5];
  const float* b2     = (const float*)d_in[6];
  const float* W3     = (const float*)d_in[7];
  const float* b3     = (const float*)d_in[8];
  const float* head_w = (const float*)d_in[9];
  const float* head_b = (const float*)d_in[10];
  float* out = (float*)d_out;

  // workspace layout (16B-aligned)
  char* ws = (char*)d_ws;
  _Float16* w1p = (_Float16*)(ws);                 // 4,194,304 B
  _Float16* w2p = (_Float16*)(ws + 4194304);       // 4,194,304 B
  _Float16* gwp = (_Float16*)(ws + 8388608);       // 8,192 B
  float*    w3h = (float*)(ws + 8396800);          // 16,384 B
  float*    c3  = (float*)(ws + 8413184);          // 64 B

  hipLaunchKernelGGL(prep_kernel, dim3(402), dim3(256), 0, stream,
                     W1, W2, W3, b3, head_w, gate_w, w1p, w2p, w3h, c3, gwp);
  hipLaunchKernelGGL(moe_main, dim3(B_TOK / TK), dim3(512), 0, stream,
                     x, b1, b2, w1p, w2p, gwp, gate_b, w3h, c3, head_b, out);
}